// Round 16
// baseline (298.263 us; speedup 1.0000x reference)
//
#include <hip/hip_runtime.h>

#define BB 32
#define SS 512
#define FF 768
#define NW 257        // W_MAX + 1
#define F4 192        // FF / 4
#define WIN 4         // s-positions per thread window
#define NWIN 128      // SS / WIN

typedef float f4v __attribute__((ext_vector_type(4)));

// ---- main: layer-mix + run-compressed segment-MEAN, conditional L/R sums ----
// grid: BB*32*3 = 3072 blocks of 256 (bid = b*96 + sg*3 + fc)
// block: 4 waves (WIN=4 s each) x 64 lanes (f4 = fc*64+lane) -> 16 s x 1KB
//
// PLAIN loads (no nontemporal): hidden_states was just rewritten by the
// harness's d_in restore -> resident in 256MB memory-side L3; NT hints
// would forfeit the L3 hit path.
__global__ __launch_bounds__(256, 8)
void k_main(const float* __restrict__ hs, const float* __restrict__ lw,
            const float* __restrict__ gm, const int* __restrict__ wid,
            float* __restrict__ out, float* __restrict__ lr,
            float* __restrict__ partials) {
    int bid = blockIdx.x;
    int fc = bid % 3;
    int sg = (bid / 3) & 31;
    int b  = bid / 96;
    int t = threadIdx.x;
    int lane = t & 63;
    int swave = t >> 6;
    int f4 = fc * 64 + lane;
    int s0 = sg * 16 + swave * 4;
    int win = s0 >> 2;                            // 0..127

    // softmax(layer_weights) * gamma
    float w0 = lw[0], w1 = lw[1], w2 = lw[2], w3 = lw[3];
    float mx = fmaxf(fmaxf(w0, w1), fmaxf(w2, w3));
    float e0 = __expf(w0 - mx), e1 = __expf(w1 - mx);
    float e2 = __expf(w2 - mx), e3 = __expf(w3 - mx);
    float g = gm[0] / (e0 + e1 + e2 + e3);
    float c0 = e0 * g, c1 = e1 * g, c2 = e2 * g, c3 = e3 * g;

    const f4v* h4 = (const f4v*)hs;
    const int ls = BB * SS * F4;                  // layer stride in 16B units
    int base = (b * SS + s0) * F4 + f4;
    const int* wrow = wid + b * SS + s0;

    int prev = wrow[0];
    bool sharedL = (s0 > 0) && (wrow[-1] == prev);
    bool sharedR = (s0 + WIN < SS) && (wrow[WIN] == wrow[WIN - 1]);

    f4v* lrw = (f4v*)lr + (size_t)(b * NWIN + win) * 2 * F4;   // [L|R]
    f4v* ob  = (f4v*)out + (size_t)b * NW * F4;

    f4v sent = {0.f, 0.f, 0.f, 0.f};
    f4v run  = {0.f, 0.f, 0.f, 0.f};
    int len = 0;
    bool first = true;

    #pragma unroll
    for (int k = 0; k < WIN; k++) {
        int idx = base + k * F4;
        f4v a  = h4[idx];
        f4v bv = h4[idx + ls];
        f4v cv = h4[idx + 2 * ls];
        f4v dv = h4[idx + 3 * ls];
        f4v v = c0 * a + c1 * bv + c2 * cv + c3 * dv;
        sent += v;
        int w = wrow[k];                          // wave-uniform
        if (k > 0 && w != prev) {
            if (first && sharedL) {
                lrw[f4] = run;                    // L[win]: word continues left
            } else {
                ob[(size_t)prev * F4 + f4] = run * (1.0f / (float)len);
            }
            first = false;
            run = v; len = 1; prev = w;
        } else {
            run += v; len++;
        }
    }
    {   // suffix run
        if (first) {                              // whole window one run
            if (sharedL) {
                lrw[f4] = run;                    // L[win] (interior/final window)
            } else if (sharedR) {
                lrw[F4 + f4] = run;               // R[win] (word starts here)
            } else {
                ob[(size_t)prev * F4 + f4] = run * (1.0f / (float)len);
            }
        } else {
            if (sharedR) {
                lrw[F4 + f4] = run;               // R[win]
            } else {
                ob[(size_t)prev * F4 + f4] = run * (1.0f / (float)len);
            }
        }
    }

    // sentence partial: reduce 4 s-waves -> partials[b][sg][f]
    __shared__ f4v sm[256];
    sm[t] = sent;
    __syncthreads();
    if (t < 64) {
        f4v tot = sm[t] + sm[t + 64] + sm[t + 128] + sm[t + 192];
        ((f4v*)partials)[((size_t)b * 32 + sg) * F4 + f4] = tot;  // f4==fc*64+t
    }
}

// ---- fixup: crossing words from L/R, zeros for empties, sentence slot 0 ----
// grid: BB*32 = 1024 blocks of 256; block -> (b, chunk); 8 words/block
// (words w2 ≡ chunk+1 mod 32) -> 2 serial binary searches per wave, 4x less
// serial LDS-latency chain than the 32-words/block version, all CUs busy.
__global__ __launch_bounds__(256, 8)
void k_fix(const int* __restrict__ wid,
           const float* __restrict__ lr,
           const float* __restrict__ partials,
           float* __restrict__ out) {
    __shared__ int ww[SS];
    int bid = blockIdx.x;
    int b = bid >> 5;
    int chunk = bid & 31;
    int t = threadIdx.x;
    ww[t]       = wid[b * SS + t];
    ww[t + 256] = wid[b * SS + t + 256];
    __syncthreads();

    int wave = t >> 6, lane = t & 63;
    const f4v* lr4 = (const f4v*)lr + (size_t)b * NWIN * 2 * F4;
    f4v* ob = (f4v*)out + (size_t)b * NW * F4;

    for (int i = wave; i < 8; i += 4) {           // 2 words per wave
        int w2 = 1 + chunk + 32 * i;              // 1..256
        // lower_bound(w2), lower_bound(w2+1) on sorted row (LDS broadcast)
        int lo = 0, hi = SS;
        while (lo < hi) { int m = (lo + hi) >> 1; if (ww[m] < w2) lo = m + 1; else hi = m; }
        int sa = lo;
        lo = 0; hi = SS;
        while (lo < hi) { int m = (lo + hi) >> 1; if (ww[m] < w2 + 1) lo = m + 1; else hi = m; }
        int se = lo - 1;

        f4v* po = ob + (size_t)w2 * F4;
        if (sa > se) {                            // empty word -> zeros
            f4v z = {0.f, 0.f, 0.f, 0.f};
            po[lane] = z; po[lane + 64] = z; po[lane + 128] = z;
        } else {
            int i0 = sa / WIN, j0 = se / WIN;
            if (i0 != j0) {                       // crossing word: R[i0] + sum L
                f4v a0 = lr4[((size_t)i0 * 2 + 1) * F4 + lane];
                f4v a1 = lr4[((size_t)i0 * 2 + 1) * F4 + lane + 64];
                f4v a2 = lr4[((size_t)i0 * 2 + 1) * F4 + lane + 128];
                for (int k = i0 + 1; k <= j0; k++) {
                    a0 += lr4[((size_t)k * 2) * F4 + lane];
                    a1 += lr4[((size_t)k * 2) * F4 + lane + 64];
                    a2 += lr4[((size_t)k * 2) * F4 + lane + 128];
                }
                float inv = 1.0f / (float)(se - sa + 1);
                po[lane] = a0 * inv; po[lane + 64] = a1 * inv; po[lane + 128] = a2 * inv;
            }
            // else: complete word, already written by k_main
        }
    }

    // sentence mean into slot 0 (chunk 0 only)
    if (chunk == 0 && t < F4) {
        const f4v* pp = (const f4v*)partials + (size_t)b * 32 * F4;
        f4v s = {0.f, 0.f, 0.f, 0.f};
        #pragma unroll
        for (int g2 = 0; g2 < 32; g2++) s += pp[(size_t)g2 * F4 + t];
        ob[t] = s * (1.0f / (float)SS);
    }
}

extern "C" void kernel_launch(void* const* d_in, const int* in_sizes, int n_in,
                              void* d_out, int out_size, void* d_ws, size_t ws_size,
                              hipStream_t stream) {
    const float* hs  = (const float*)d_in[0];   // (L,B,S,F) f32
    const float* lw  = (const float*)d_in[1];   // (L,)
    const float* gm  = (const float*)d_in[2];   // (1,)
    const int*   wid = (const int*)d_in[3];     // (B,S) int32, sorted per row
    float* out = (float*)d_out;                 // (B, 257, F) f32

    float* lr       = (float*)d_ws;                          // BB*NWIN*2*FF f32 = 25 MB
    float* partials = lr + (size_t)BB * NWIN * 2 * FF;       // BB*32*FF f32 = 3.1 MB

    k_main<<<BB * 96, 256, 0, stream>>>(hs, lw, gm, wid, out, lr, partials);
    k_fix<<<BB * 32, 256, 0, stream>>>(wid, lr, partials, out);
}

// Round 17
// 288.840 us; speedup vs baseline: 1.0326x; 1.0326x over previous
//
#include <hip/hip_runtime.h>

#define BB 32
#define SS 512
#define FF 768
#define NW 257        // W_MAX + 1
#define F4 192        // FF / 4
#define WIN 8         // s-positions per thread window
#define NWIN 64       // SS / WIN

typedef float f4v __attribute__((ext_vector_type(4)));

// ---- main: layer-mix + run-compressed segment-MEAN, L/R window sums ----
// grid: BB*16*3 blocks of 256 (bid = b*48 + sg*3 + fc)
// block: 4 waves(swave: 8 s each) x 64 lanes(f4 = fc*64+lane) -> 32 s x 1KB
//
// Every window writes L[b][win] (prefix-run sum) and R[b][win] (suffix-run
// sum) unconditionally -> unique writer, no atomics, no zero-init.
// Complete-inside-window words: direct mean store to out.
// Boundary-crossing words: k_fix computes R[i] + sum L[i+1..j].
__global__ __launch_bounds__(256, 6)
void k_main(const float* __restrict__ hs, const float* __restrict__ lw,
            const float* __restrict__ gm, const int* __restrict__ wid,
            float* __restrict__ out, float* __restrict__ lr,
            float* __restrict__ partials) {
    int bid = blockIdx.x;
    int fc = bid % 3;
    int sg = (bid / 3) & 15;
    int b  = bid / 48;
    int t = threadIdx.x;
    int lane = t & 63;
    int swave = t >> 6;
    int f4 = fc * 64 + lane;
    int s0 = sg * 32 + swave * 8;
    int win = s0 >> 3;                            // 0..63

    // softmax(layer_weights) * gamma
    float w0 = lw[0], w1 = lw[1], w2 = lw[2], w3 = lw[3];
    float mx = fmaxf(fmaxf(w0, w1), fmaxf(w2, w3));
    float e0 = __expf(w0 - mx), e1 = __expf(w1 - mx);
    float e2 = __expf(w2 - mx), e3 = __expf(w3 - mx);
    float g = gm[0] / (e0 + e1 + e2 + e3);
    float c0 = e0 * g, c1 = e1 * g, c2 = e2 * g, c3 = e3 * g;

    const f4v* h4 = (const f4v*)hs;
    const int ls = BB * SS * F4;                  // layer stride in 16B units
    int base = (b * SS + s0) * F4 + f4;
    const int* wrow = wid + b * SS + s0;

    int prev = wrow[0];
    bool sharedL = (s0 > 0) && (wrow[-1] == prev);
    bool sharedR = (s0 + WIN < SS) && (wrow[WIN] == wrow[WIN - 1]);

    f4v* lrw = (f4v*)lr + (size_t)(b * NWIN + win) * 2 * F4;   // [L|R] this window
    f4v* ob  = (f4v*)out + (size_t)b * NW * F4;

    f4v sent = {0.f, 0.f, 0.f, 0.f};
    f4v run  = {0.f, 0.f, 0.f, 0.f};
    int len = 0;
    bool first = true;

    #pragma unroll
    for (int k = 0; k < WIN; k++) {
        int idx = base + k * F4;
        f4v a  = __builtin_nontemporal_load(&h4[idx]);
        f4v bv = __builtin_nontemporal_load(&h4[idx + ls]);
        f4v cv = __builtin_nontemporal_load(&h4[idx + 2 * ls]);
        f4v dv = __builtin_nontemporal_load(&h4[idx + 3 * ls]);
        f4v v = c0 * a + c1 * bv + c2 * cv + c3 * dv;
        sent += v;
        int w = wrow[k];                          // wave-uniform
        if (k > 0 && w != prev) {
            if (first) {
                lrw[f4] = run;                    // L[win] = prefix-run sum
                if (!sharedL)                     // complete word at left edge
                    ob[(size_t)prev * F4 + f4] = run * (1.0f / (float)len);
            } else {                              // middle run: complete word
                ob[(size_t)prev * F4 + f4] = run * (1.0f / (float)len);
            }
            first = false;
            run = v; len = 1; prev = w;
        } else {
            run += v; len++;
        }
    }
    {   // suffix run
        lrw[F4 + f4] = run;                       // R[win]
        if (first) {                              // single-run window: L = R
            lrw[f4] = run;
            if (!sharedL && !sharedR)
                ob[(size_t)prev * F4 + f4] = run * (1.0f / (float)len);
        } else if (!sharedR) {
            ob[(size_t)prev * F4 + f4] = run * (1.0f / (float)len);
        }
    }

    // sentence partial: reduce 4 s-waves -> partials[b][sg][f]
    __shared__ f4v sm[256];
    sm[t] = sent;
    __syncthreads();
    if (t < 64) {
        f4v tot = sm[t] + sm[t + 64] + sm[t + 128] + sm[t + 192];
        ((f4v*)partials)[((size_t)b * 16 + sg) * F4 + f4] = tot;  // f4==fc*64+t
    }
}

// ---- fixup: crossing words from L/R, zeros for empties, sentence slot 0 ----
// grid: BB*8 blocks of 256; block -> (b, chunk); words w ≡ chunk (mod 8)
__global__ __launch_bounds__(256, 4)
void k_fix(const int* __restrict__ wid,
           const float* __restrict__ lr,
           const float* __restrict__ partials,
           float* __restrict__ out) {
    __shared__ int ww[SS];
    int bid = blockIdx.x;
    int b = bid >> 3;
    int chunk = bid & 7;
    int t = threadIdx.x;
    ww[t]       = wid[b * SS + t];
    ww[t + 256] = wid[b * SS + t + 256];
    __syncthreads();

    int wave = t >> 6, lane = t & 63;
    const f4v* lr4 = (const f4v*)lr + (size_t)b * NWIN * 2 * F4;
    f4v* ob = (f4v*)out + (size_t)b * NW * F4;

    for (int i = wave; i < 32; i += 4) {
        int w2 = 1 + chunk + 8 * i;               // 1..256
        // lower_bound(w2), lower_bound(w2+1) on sorted row (LDS broadcast)
        int lo = 0, hi = SS;
        while (lo < hi) { int m = (lo + hi) >> 1; if (ww[m] < w2) lo = m + 1; else hi = m; }
        int sa = lo;
        lo = 0; hi = SS;
        while (lo < hi) { int m = (lo + hi) >> 1; if (ww[m] < w2 + 1) lo = m + 1; else hi = m; }
        int se = lo - 1;

        f4v* po = ob + (size_t)w2 * F4;
        if (sa > se) {                            // empty word -> zeros
            f4v z = {0.f, 0.f, 0.f, 0.f};
            po[lane] = z; po[lane + 64] = z; po[lane + 128] = z;
        } else {
            int i0 = sa >> 3, j0 = se >> 3;
            if (i0 != j0) {                       // crossing word: R[i0] + sum L
                f4v a0 = lr4[((size_t)i0 * 2 + 1) * F4 + lane];
                f4v a1 = lr4[((size_t)i0 * 2 + 1) * F4 + lane + 64];
                f4v a2 = lr4[((size_t)i0 * 2 + 1) * F4 + lane + 128];
                for (int k = i0 + 1; k <= j0; k++) {
                    a0 += lr4[((size_t)k * 2) * F4 + lane];
                    a1 += lr4[((size_t)k * 2) * F4 + lane + 64];
                    a2 += lr4[((size_t)k * 2) * F4 + lane + 128];
                }
                float inv = 1.0f / (float)(se - sa + 1);
                po[lane] = a0 * inv; po[lane + 64] = a1 * inv; po[lane + 128] = a2 * inv;
            }
            // else: complete word, already written by k_main
        }
    }

    // sentence mean into slot 0 (chunk 0 only)
    if (chunk == 0 && t < F4) {
        const f4v* pp = (const f4v*)partials + (size_t)b * 16 * F4;
        f4v s = {0.f, 0.f, 0.f, 0.f};
        #pragma unroll
        for (int g2 = 0; g2 < 16; g2++) s += pp[(size_t)g2 * F4 + t];
        ob[t] = s * (1.0f / (float)SS);
    }
}

extern "C" void kernel_launch(void* const* d_in, const int* in_sizes, int n_in,
                              void* d_out, int out_size, void* d_ws, size_t ws_size,
                              hipStream_t stream) {
    const float* hs  = (const float*)d_in[0];   // (L,B,S,F) f32
    const float* lw  = (const float*)d_in[1];   // (L,)
    const float* gm  = (const float*)d_in[2];   // (1,)
    const int*   wid = (const int*)d_in[3];     // (B,S) int32, sorted per row
    float* out = (float*)d_out;                 // (B, 257, F) f32

    float* lr       = (float*)d_ws;                          // BB*NWIN*2*FF f32 = 12.6 MB
    float* partials = lr + (size_t)BB * NWIN * 2 * FF;       // BB*16*FF f32 = 1.6 MB

    k_main<<<BB * 48, 256, 0, stream>>>(hs, lw, gm, wid, out, lr, partials);
    k_fix<<<BB * 8, 256, 0, stream>>>(wid, lr, partials, out);
}